// Round 16
// baseline (42.888 us; speedup 1.0000x reference)
//
#include <hip/hip_runtime.h>
#include <hip/hip_fp16.h>
#include <math.h>

#define IMG_H 512
#define IMG_W 512
#define CH    3
#define TILE_W 16
#define TILE_H 64                // per-tile: four 16-row quarters (A,B,C,D)
#define NT    2                  // vertical tiles per block (double-buffered)
#define QTR   16
#define PAD   2
#define TP    20                 // padded per-quarter tile: 20 rows x 20 cols

#if __has_builtin(__builtin_amdgcn_rcpf)
#define RCP(x) __builtin_amdgcn_rcpf(x)
#else
#define RCP(x) (1.0f / (x))
#endif

__device__ __forceinline__ int reflect_idx(int i, int n) {
    i = (i < 0) ? -i : i;
    i = (i >= n) ? (2 * n - 2 - i) : i;
    return i;
}

__device__ __forceinline__ __half2 bch(unsigned int u) {
    return __builtin_bit_cast(__half2, u);
}
__device__ __forceinline__ unsigned int hcb(__half2 h) {
    return __builtin_bit_cast(unsigned int, h);
}

__global__ __launch_bounds__(256)
void bilateral_kernel(const float* __restrict__ in, float* __restrict__ out) {
    // R15 quad-f16 structure + intra-block tile pipeline:
    //   while computing tile t from buf[t&1], tile t+1's global loads are
    //   issued BEFORE the tap loop (latency hides under 15 taps) and the
    //   convert+ds_write lands in buf[(t+1)&1] between tap rows.
    // Two 12-float staging chunks bound register liveness (<=64 VGPR goal).
    __shared__ uint4 H4[NT][TP][TP];   // (x_AB, x_CD, y_AB, y_CD) half2 quads
    __shared__ uint2 H2[NT][TP][TP];   // (z_AB, z_CD)

    const int b   = blockIdx.z;
    const int by0 = blockIdx.y * (TILE_H * NT);
    const int bx  = blockIdx.x * TILE_W;
    const int tx  = threadIdx.x;
    const int ty  = threadIdx.y;
    const int tid = ty * TILE_W + tx;

    // Staging entry coords (400 entries, 2 chunks/thread; chunk1 for tid<144).
    const int i1  = tid + 256;
    const int r0e = tid / TP, c0e = tid - r0e * TP;
    const int r1e = i1  / TP, c1e = i1  - r1e * TP;
    const bool a1 = (i1 < TP * TP);
    const int gx0 = reflect_idx(bx + c0e - PAD, IMG_W);
    const int gx1 = reflect_idx(bx + c1e - PAD, IMG_W);

    float s0v[12], s1v[12];

#define ISSUE(t, re, gx, act, dst)                                           \
    do { _Pragma("unroll")                                                   \
        for (int q = 0; q < 4; ++q) {                                        \
            const int gy = reflect_idx(by0 + (t) * TILE_H + q * QTR + (re) - PAD, IMG_H); \
            const float* p = in + ((size_t)(b * IMG_H + gy) * IMG_W + (gx)) * CH; \
            if (act) { (dst)[q*3+0] = p[0]; (dst)[q*3+1] = p[1]; (dst)[q*3+2] = p[2]; } \
        } } while (0)

#define STORE_LDS(t, re, ce, act, src)                                       \
    do { if (act) {                                                          \
        uint4 h4; uint2 h2;                                                  \
        h4.x = hcb(__floats2half2_rn((src)[0], (src)[3]));                   \
        h4.y = hcb(__floats2half2_rn((src)[6], (src)[9]));                   \
        h4.z = hcb(__floats2half2_rn((src)[1], (src)[4]));                   \
        h4.w = hcb(__floats2half2_rn((src)[7], (src)[10]));                  \
        h2.x = hcb(__floats2half2_rn((src)[2], (src)[5]));                   \
        h2.y = hcb(__floats2half2_rn((src)[8], (src)[11]));                  \
        H4[(t) & 1][re][ce] = h4; H2[(t) & 1][re][ce] = h2; } } while (0)

    // Prologue: stage tile 0 into buf0.
    ISSUE(0, r0e, gx0, true, s0v);
    ISSUE(0, r1e, gx1, a1, s1v);
    STORE_LDS(0, r0e, c0e, true, s0v);
    STORE_LDS(0, r1e, c1e, a1, s1v);
    __syncthreads();

    // Row permutation: ty 0..3 -> rows 0,4,8,12 within each wave (conflict-free,
    // proven 0 conflicts in R3/R6/R12/R15 at stride 20 entries).
    const int rp = ((ty & 3) << 2) | (ty >> 2);

    // arg = K2*d2 + log2(spatial); K2 = -log2(e)/(2*0.04^2).
    const __half2 K2 = __float2half2_rn(-450.8422f);
    const __half2 B2[3][3] = {
        { __float2half2_rn(-8.395800f), __float2half2_rn(-6.231757f), __float2half2_rn(-5.510409f) },
        { __float2half2_rn(-6.231757f), __float2half2_rn(-4.067714f), __float2half2_rn(-3.346367f) },
        { __float2half2_rn(-5.510409f), __float2half2_rn(-3.346367f), __float2half2_rn(-2.625024f) },
    };

    #pragma unroll
    for (int t = 0; t < NT; ++t) {
        const uint4 cP = H4[t & 1][rp + PAD][tx + PAD];
        const uint2 cQ = H2[t & 1][rp + PAD][tx + PAD];
        const __half2 cxAB = bch(cP.x), cxCD = bch(cP.y);
        const __half2 cyAB = bch(cP.z), cyCD = bch(cP.w);
        const __half2 czAB = bch(cQ.x), czCD = bch(cQ.y);

        const __half2 z2 = __float2half2_rn(0.0f);
        __half2 nxAB = z2, nyAB = z2, nzAB = z2, ndAB = z2;
        __half2 nxCD = z2, nyCD = z2, nzCD = z2, ndCD = z2;

#define TAPROW(dy)                                                           \
        { const int iy = ((dy) < 3) ? (dy) : 4 - (dy);                       \
          _Pragma("unroll")                                                  \
          for (int k = 0; k < 5; ++k) {                                      \
            const int ix = (k < 3) ? k : 4 - k;                              \
            const uint4 P = H4[t & 1][rp + (dy)][tx + k];                    \
            const uint2 Q = H2[t & 1][rp + (dy)][tx + k];                    \
            const __half2 sxAB = bch(P.x), sxCD = bch(P.y);                  \
            const __half2 syAB = bch(P.z), syCD = bch(P.w);                  \
            const __half2 szAB = bch(Q.x), szCD = bch(Q.y);                  \
            {                                                                \
                const __half2 dx = __hsub2(sxAB, cxAB);                      \
                const __half2 dh = __hsub2(syAB, cyAB);                      \
                const __half2 dz = __hsub2(szAB, czAB);                      \
                const __half2 d2 = __hfma2(dx, dx, __hfma2(dh, dh, __hmul2(dz, dz))); \
                const __half2 w = h2exp2(__hfma2(d2, K2, B2[iy][ix]));       \
                nxAB = __hfma2(w, sxAB, nxAB);                               \
                nyAB = __hfma2(w, syAB, nyAB);                               \
                nzAB = __hfma2(w, szAB, nzAB);                               \
                ndAB = __hadd2(ndAB, w);                                     \
            }                                                                \
            {                                                                \
                const __half2 dx = __hsub2(sxCD, cxCD);                      \
                const __half2 dh = __hsub2(syCD, cyCD);                      \
                const __half2 dz = __hsub2(szCD, czCD);                      \
                const __half2 d2 = __hfma2(dx, dx, __hfma2(dh, dh, __hmul2(dz, dz))); \
                const __half2 w = h2exp2(__hfma2(d2, K2, B2[iy][ix]));       \
                nxCD = __hfma2(w, sxCD, nxCD);                               \
                nyCD = __hfma2(w, syCD, nyCD);                               \
                nzCD = __hfma2(w, szCD, nzCD);                               \
                ndCD = __hadd2(ndCD, w);                                     \
            }                                                                \
          } }

        // T14 split: issue next tile's chunk-0 loads, compute 15 taps (hides
        // HBM latency), convert+write chunk 0; issue chunk 1, compute 10 taps,
        // write chunk 1. All into buf[(t+1)&1] -> no ordering vs current reads.
        if (t + 1 < NT) ISSUE(t + 1, r0e, gx0, true, s0v);
        TAPROW(0) TAPROW(1) TAPROW(2)
        if (t + 1 < NT) { STORE_LDS(t + 1, r0e, c0e, true, s0v); ISSUE(t + 1, r1e, gx1, a1, s1v); }
        TAPROW(3) TAPROW(4)
        if (t + 1 < NT) STORE_LDS(t + 1, r1e, c1e, a1, s1v);
#undef TAPROW

        // Epilogue: 4 quad pixels.
        const int xcol = bx + tx;
        #pragma unroll
        for (int q = 0; q < 4; ++q) {
            float n0, n1, n2, den;
            if (q == 0)      { n0 = __low2float(nxAB);  n1 = __low2float(nyAB);  n2 = __low2float(nzAB);  den = __low2float(ndAB); }
            else if (q == 1) { n0 = __high2float(nxAB); n1 = __high2float(nyAB); n2 = __high2float(nzAB); den = __high2float(ndAB); }
            else if (q == 2) { n0 = __low2float(nxCD);  n1 = __low2float(nyCD);  n2 = __low2float(nzCD);  den = __low2float(ndCD); }
            else             { n0 = __high2float(nxCD); n1 = __high2float(nyCD); n2 = __high2float(nzCD); den = __high2float(ndCD); }
            const float inv = RCP(den);
            const int y = by0 + t * TILE_H + q * QTR + rp;
            float* dst = out + ((size_t)(b * IMG_H + y) * IMG_W + xcol) * CH;
            dst[0] = fminf(fmaxf(n0 * inv, 0.0f), 1.0f);
            dst[1] = fminf(fmaxf(n1 * inv, 0.0f), 1.0f);
            dst[2] = fminf(fmaxf(n2 * inv, 0.0f), 1.0f);
        }

        __syncthreads();   // buf[(t+1)&1] fully written before next iter reads
    }
}

extern "C" void kernel_launch(void* const* d_in, const int* in_sizes, int n_in,
                              void* d_out, int out_size, void* d_ws, size_t ws_size,
                              hipStream_t stream) {
    const float* in = (const float*)d_in[0];
    float* out = (float*)d_out;
    const int B = in_sizes[0] / (IMG_H * IMG_W * CH);   // 16

    dim3 block(TILE_W, 16, 1);
    dim3 grid(IMG_W / TILE_W, IMG_H / (TILE_H * NT), B);   // 32 x 4 x 16
    bilateral_kernel<<<grid, block, 0, stream>>>(in, out);
}

// Round 17
// 38.697 us; speedup vs baseline: 1.1083x; 1.1083x over previous
//
#include <hip/hip_runtime.h>
#include <hip/hip_fp16.h>
#include <math.h>

#define IMG_H 512
#define IMG_W 512
#define CH    3
#define TILE_W 16
#define TILE_H 64                // four 16-row quarters (A,B,C,D)
#define QTR   16
#define PAD   2
#define TP    20                 // padded per-quarter tile: 20 rows x 20 cols

#if __has_builtin(__builtin_amdgcn_rcpf)
#define RCP(x) __builtin_amdgcn_rcpf(x)
#else
#define RCP(x) (1.0f / (x))
#endif

__device__ __forceinline__ int reflect_idx(int i, int n) {
    i = (i < 0) ? -i : i;
    i = (i >= n) ? (2 * n - 2 - i) : i;
    return i;
}

__device__ __forceinline__ __half2 bch(unsigned int u) {
    return __builtin_bit_cast(__half2, u);
}
__device__ __forceinline__ unsigned int hcb(__half2 h) {
    return __builtin_bit_cast(unsigned int, h);
}

__global__ __launch_bounds__(256)
void bilateral_kernel(const float* __restrict__ in, float* __restrict__ out) {
    // R15 quad-f16 layout (4 px/thread, quarters A..D interleaved in half2):
    //   H4[r][c] = (x_AB, x_CD, y_AB, y_CD)   H2[r][c] = (z_AB, z_CD)
    // NEW: hand-written depth-1 row double-buffer. Named register arrays
    // (PA/QA, PB/QB) rotate across the 5 window rows so each compute row
    // (~90 VALU cyc) covers the next row's 10 ds_reads (~120 cyc latency).
    // Liveness bounded by construction: 2 rows x 30 dwords -> no R13/R16-style
    // hoisting blowup. Stride-20 + rp permutation: proven conflict-free.
    __shared__ uint4 H4[TP][TP];   // 6.4 KB
    __shared__ uint2 H2[TP][TP];   // 3.2 KB

    const int b  = blockIdx.z;
    const int by = blockIdx.y * TILE_H;
    const int bx = blockIdx.x * TILE_W;
    const int tx = threadIdx.x;
    const int ty = threadIdx.y;
    const int tid = ty * TILE_W + tx;

    // Staging: 400 entries, each covers 4 pixels (quarters A..D).
    for (int i = tid; i < TP * TP; i += 256) {
        const int r  = i / TP;
        const int cc = i - r * TP;
        const int gx  = reflect_idx(bx + cc - PAD, IMG_W);
        const int gyA = reflect_idx(by + r - PAD, IMG_H);
        const int gyB = reflect_idx(by + QTR + r - PAD, IMG_H);
        const int gyC = reflect_idx(by + 2 * QTR + r - PAD, IMG_H);
        const int gyD = reflect_idx(by + 3 * QTR + r - PAD, IMG_H);
        const float* pA = in + ((size_t)(b * IMG_H + gyA) * IMG_W + gx) * CH;
        const float* pB = in + ((size_t)(b * IMG_H + gyB) * IMG_W + gx) * CH;
        const float* pC = in + ((size_t)(b * IMG_H + gyC) * IMG_W + gx) * CH;
        const float* pD = in + ((size_t)(b * IMG_H + gyD) * IMG_W + gx) * CH;
        uint4 h4;
        uint2 h2;
        h4.x = hcb(__floats2half2_rn(pA[0], pB[0]));
        h4.y = hcb(__floats2half2_rn(pC[0], pD[0]));
        h4.z = hcb(__floats2half2_rn(pA[1], pB[1]));
        h4.w = hcb(__floats2half2_rn(pC[1], pD[1]));
        h2.x = hcb(__floats2half2_rn(pA[2], pB[2]));
        h2.y = hcb(__floats2half2_rn(pC[2], pD[2]));
        H4[r][cc] = h4;
        H2[r][cc] = h2;
    }
    __syncthreads();

    // Row permutation: ty 0..3 -> rows 0,4,8,12 within each wave (conflict-free).
    const int rp = ((ty & 3) << 2) | (ty >> 2);

    // arg = K2*d2 + log2(spatial); K2 = -log2(e)/(2*0.04^2).
    const __half2 K2 = __float2half2_rn(-450.8422f);
    const __half2 B2[3][3] = {
        { __float2half2_rn(-8.395800f), __float2half2_rn(-6.231757f), __float2half2_rn(-5.510409f) },
        { __float2half2_rn(-6.231757f), __float2half2_rn(-4.067714f), __float2half2_rn(-3.346367f) },
        { __float2half2_rn(-5.510409f), __float2half2_rn(-3.346367f), __float2half2_rn(-2.625024f) },
    };

    const uint4 cP = H4[rp + PAD][tx + PAD];
    const uint2 cQ = H2[rp + PAD][tx + PAD];
    const __half2 cxAB = bch(cP.x), cxCD = bch(cP.y);
    const __half2 cyAB = bch(cP.z), cyCD = bch(cP.w);
    const __half2 czAB = bch(cQ.x), czCD = bch(cQ.y);

    const __half2 z2 = __float2half2_rn(0.0f);
    __half2 nxAB = z2, nyAB = z2, nzAB = z2, ndAB = z2;
    __half2 nxCD = z2, nyCD = z2, nzCD = z2, ndCD = z2;

    uint4 PA[5], PB[5];
    uint2 QA[5], QB[5];

#define LOADROW(dy, P_, Q_)                                                  \
    { _Pragma("unroll")                                                      \
      for (int k = 0; k < 5; ++k) {                                          \
          P_[k] = H4[rp + (dy)][tx + k];                                     \
          Q_[k] = H2[rp + (dy)][tx + k];                                     \
      } }

#define COMPROW(dy, P_, Q_)                                                  \
    { const int iy = ((dy) < 3) ? (dy) : 4 - (dy);                           \
      _Pragma("unroll")                                                      \
      for (int k = 0; k < 5; ++k) {                                          \
          const int ix = (k < 3) ? k : 4 - k;                                \
          const __half2 sxAB = bch(P_[k].x), sxCD = bch(P_[k].y);            \
          const __half2 syAB = bch(P_[k].z), syCD = bch(P_[k].w);            \
          const __half2 szAB = bch(Q_[k].x), szCD = bch(Q_[k].y);            \
          {                                                                  \
              const __half2 dx = __hsub2(sxAB, cxAB);                        \
              const __half2 dh = __hsub2(syAB, cyAB);                        \
              const __half2 dz = __hsub2(szAB, czAB);                        \
              const __half2 d2 = __hfma2(dx, dx, __hfma2(dh, dh, __hmul2(dz, dz))); \
              const __half2 w = h2exp2(__hfma2(d2, K2, B2[iy][ix]));         \
              nxAB = __hfma2(w, sxAB, nxAB);                                 \
              nyAB = __hfma2(w, syAB, nyAB);                                 \
              nzAB = __hfma2(w, szAB, nzAB);                                 \
              ndAB = __hadd2(ndAB, w);                                       \
          }                                                                  \
          {                                                                  \
              const __half2 dx = __hsub2(sxCD, cxCD);                        \
              const __half2 dh = __hsub2(syCD, cyCD);                        \
              const __half2 dz = __hsub2(szCD, czCD);                        \
              const __half2 d2 = __hfma2(dx, dx, __hfma2(dh, dh, __hmul2(dz, dz))); \
              const __half2 w = h2exp2(__hfma2(d2, K2, B2[iy][ix]));         \
              nxCD = __hfma2(w, sxCD, nxCD);                                 \
              nyCD = __hfma2(w, syCD, nyCD);                                 \
              nzCD = __hfma2(w, szCD, nzCD);                                 \
              ndCD = __hadd2(ndCD, w);                                       \
          }                                                                  \
      } }

    // Depth-1 software pipeline over the 5 window rows.
    LOADROW(0, PA, QA)
    LOADROW(1, PB, QB)
    COMPROW(0, PA, QA)
    LOADROW(2, PA, QA)
    COMPROW(1, PB, QB)
    LOADROW(3, PB, QB)
    COMPROW(2, PA, QA)
    LOADROW(4, PA, QA)
    COMPROW(3, PB, QB)
    COMPROW(4, PA, QA)

#undef LOADROW
#undef COMPROW

    const int xcol = bx + tx;
    #pragma unroll
    for (int q = 0; q < 4; ++q) {
        float n0, n1, n2, den;
        if (q == 0)      { n0 = __low2float(nxAB);  n1 = __low2float(nyAB);  n2 = __low2float(nzAB);  den = __low2float(ndAB); }
        else if (q == 1) { n0 = __high2float(nxAB); n1 = __high2float(nyAB); n2 = __high2float(nzAB); den = __high2float(ndAB); }
        else if (q == 2) { n0 = __low2float(nxCD);  n1 = __low2float(nyCD);  n2 = __low2float(nzCD);  den = __low2float(ndCD); }
        else             { n0 = __high2float(nxCD); n1 = __high2float(nyCD); n2 = __high2float(nzCD); den = __high2float(ndCD); }
        const float inv = RCP(den);
        const int y = by + q * QTR + rp;
        float* dst = out + ((size_t)(b * IMG_H + y) * IMG_W + xcol) * CH;
        dst[0] = fminf(fmaxf(n0 * inv, 0.0f), 1.0f);
        dst[1] = fminf(fmaxf(n1 * inv, 0.0f), 1.0f);
        dst[2] = fminf(fmaxf(n2 * inv, 0.0f), 1.0f);
    }
}

extern "C" void kernel_launch(void* const* d_in, const int* in_sizes, int n_in,
                              void* d_out, int out_size, void* d_ws, size_t ws_size,
                              hipStream_t stream) {
    const float* in = (const float*)d_in[0];
    float* out = (float*)d_out;
    const int B = in_sizes[0] / (IMG_H * IMG_W * CH);   // 16

    dim3 block(TILE_W, 16, 1);
    dim3 grid(IMG_W / TILE_W, IMG_H / TILE_H, B);       // 32 x 8 x 16
    bilateral_kernel<<<grid, block, 0, stream>>>(in, out);
}